// Round 9
// baseline (141.987 us; speedup 1.0000x reference)
//
#include <hip/hip_runtime.h>
#include <hip/hip_bf16.h>

#define NNODES 50000
#define NEDGES 640000
#define HID 128

typedef __attribute__((ext_vector_type(8)))  short  short8;
typedef __attribute__((ext_vector_type(16))) float  f32x16;
typedef __attribute__((ext_vector_type(4)))  float  f32x4v;
typedef __attribute__((ext_vector_type(4)))  unsigned int u32x4;

static __device__ __forceinline__ short f2bf(float x) {
    return __builtin_bit_cast(short, __float2bfloat16(x));
}

// =====================================================================
// Kernel 1: pre = [h*W1u + b1 | h*W1v], quantized to uint8 (bias 128)
// with per-(node,half) scale = rowmax/127 (f32, separate arrays).
// 2 col-half blocks: 32KB LDS, grid 782, 3 blk/CU -> single wave of blocks.
// =====================================================================
__global__ __launch_bounds__(256, 3)
void gemm_pre(const float* __restrict__ h,
              const float* __restrict__ W1,
              const float* __restrict__ b1,
              unsigned char* __restrict__ pre8,
              float* __restrict__ sU,
              float* __restrict__ sV)
{
    __shared__ short8 w1s8[128 * 16];   // 32 KB swizzled
    short* w1s = (short*)w1s8;
    const int tid  = threadIdx.x;
    const int mblk = blockIdx.x >> 1;
    const int ch   = blockIdx.x & 1;    // 0: u-half (+b1), 1: v-half

    for (int idx = tid; idx < 128 * 128; idx += 256) {
        int k = idx >> 7, col = idx & 127;
        float val = W1[(ch * 128 + k) * HID + col];
        int c = (k >> 3) ^ (col & 7);
        w1s[col * 128 + c * 8 + (k & 7)] = f2bf(val);
    }
    __syncthreads();

    const int lane = tid & 63;
    const int wid  = tid >> 6;
    const int l31  = lane & 31;
    const int grp  = lane >> 5;

    const int mb = mblk * 128 + wid * 32;
    int arow = mb + l31;
    if (arow > NNODES - 1) arow = NNODES - 1;
    const float* ap = h + (size_t)arow * HID + grp * 8;

    f32x16 acc[4];
    #pragma unroll
    for (int nt = 0; nt < 4; ++nt)
        #pragma unroll
        for (int r = 0; r < 16; ++r) acc[nt][r] = 0.f;

    #pragma unroll
    for (int ks = 0; ks < 8; ++ks) {
        f32x4v a0 = *(const f32x4v*)(ap + ks * 16);
        f32x4v a1 = *(const f32x4v*)(ap + ks * 16 + 4);
        short8 af;
        af[0] = f2bf(a0.x); af[1] = f2bf(a0.y); af[2] = f2bf(a0.z); af[3] = f2bf(a0.w);
        af[4] = f2bf(a1.x); af[5] = f2bf(a1.y); af[6] = f2bf(a1.z); af[7] = f2bf(a1.w);
        #pragma unroll
        for (int nt = 0; nt < 4; ++nt) {
            const int col = nt * 32 + l31;
            short8 bf = w1s8[col * 16 + ((ks * 2 + grp) ^ (col & 7))];
            acc[nt] = __builtin_amdgcn_mfma_f32_32x32x16_bf16(af, bf, acc[nt], 0, 0, 0);
        }
    }

    float b1v[4];
    #pragma unroll
    for (int nt = 0; nt < 4; ++nt)
        b1v[nt] = ch ? 0.f : b1[nt * 32 + l31];

    // epilogue: add bias, per-row absmax (cols are l31 x nt), quantize
    #pragma unroll
    for (int r = 0; r < 16; ++r) {
        float m = 0.f;
        #pragma unroll
        for (int nt = 0; nt < 4; ++nt) {
            float val = acc[nt][r] + b1v[nt];
            acc[nt][r] = val;
            m = fmaxf(m, fabsf(val));
        }
        m = fmaxf(m, __shfl_xor(m, 1, 64));
        m = fmaxf(m, __shfl_xor(m, 2, 64));
        m = fmaxf(m, __shfl_xor(m, 4, 64));
        m = fmaxf(m, __shfl_xor(m, 8, 64));
        m = fmaxf(m, __shfl_xor(m, 16, 64));

        const int row = mb + ((r & 3) + 8 * (r >> 2) + 4 * grp);
        if (row < NNODES) {
            const float inv = (m > 0.f) ? (127.f / m) : 0.f;
            if (l31 == 0) (ch ? sV : sU)[row] = m * (1.f / 127.f);
            #pragma unroll
            for (int nt = 0; nt < 4; ++nt) {
                int q = (int)rintf(acc[nt][r] * inv) + 128;
                pre8[(size_t)row * 256 + ch * 128 + nt * 32 + l31] = (unsigned char)q;
            }
        }
    }
}

// =====================================================================
// Kernel 2: per-edge apply on int8 pre. 8 lanes/edge, 16 cols each.
// Pipeline: idx[i+2] / scale+gather[i+1] / compute[i].
// 1250 blocks x 32 edges x 16 iters = 640000 exactly; all blocks
// co-resident at 6 blk/CU (launch_bounds(256,6), VGPR cap 85 >> 52 used).
// =====================================================================
#define NBLK 1250
#define EPI  32
#define ESTRIDE (NBLK * EPI)
#define NITER 16

__global__ __launch_bounds__(256, 6)
void edge_apply(const unsigned char* __restrict__ pre8,
                const float* __restrict__ sU,
                const float* __restrict__ sV,
                const int* __restrict__ ei,
                const float* __restrict__ ea,
                const float* __restrict__ W1,
                const float* __restrict__ W2,
                const float* __restrict__ b2,
                float* __restrict__ out)
{
    const int tid = threadIdx.x;
    const int sub = tid & 7;
    const int e0  = blockIdx.x * EPI + (tid >> 3);

    float r256v[16], r257v[16], w2v[16];
    #pragma unroll
    for (int q = 0; q < 4; ++q) {
        f32x4v a = *(const f32x4v*)(W1 + 256 * HID + sub * 16 + q * 4);
        f32x4v b = *(const f32x4v*)(W1 + 257 * HID + sub * 16 + q * 4);
        f32x4v c = *(const f32x4v*)(W2 + sub * 16 + q * 4);
        r256v[q*4+0]=a.x; r256v[q*4+1]=a.y; r256v[q*4+2]=a.z; r256v[q*4+3]=a.w;
        r257v[q*4+0]=b.x; r257v[q*4+1]=b.y; r257v[q*4+2]=b.z; r257v[q*4+3]=b.w;
        w2v [q*4+0]=c.x; w2v [q*4+1]=c.y; w2v [q*4+2]=c.z; w2v [q*4+3]=c.w;
    }
    const float b2v = b2[0];

    const bool is64 = (ei[1] == 0) && (ei[3] == 0) && (ei[5] == 0) && (ei[7] == 0);
    const long long* ei64 = (const long long*)ei;

    int   uu[3], vv[3];
    float a0v[3], a1v[3];
    float su[2], sv[2];
    u32x4 gu[2], gv[2];

    #pragma unroll
    for (int p = 0; p < 2; ++p) {
        const int ee = e0 + p * ESTRIDE;
        uu[p]  = is64 ? (int)ei64[ee] : ei[ee];
        vv[p]  = is64 ? (int)ei64[NEDGES + ee] : ei[NEDGES + ee];
        a0v[p] = ea[2 * ee]; a1v[p] = ea[2 * ee + 1];
    }
    su[0] = sU[uu[0]]; sv[0] = sV[vv[0]];
    gu[0] = *(const u32x4*)(pre8 + (size_t)uu[0] * 256 + sub * 16);
    gv[0] = *(const u32x4*)(pre8 + (size_t)vv[0] * 256 + 128 + sub * 16);

    #pragma unroll
    for (int i = 0; i < NITER; ++i) {
        const int cur = i % 3, nxt = (i + 1) % 3, nx2 = (i + 2) % 3;
        const int cb = i & 1, nb = (i + 1) & 1;

        // prefetch idx bundle i+2 (clamped to a valid edge; unused at tail)
        {
            const int ee = (i + 2 < NITER) ? (e0 + (i + 2) * ESTRIDE) : e0;
            uu[nx2]  = is64 ? (int)ei64[ee] : ei[ee];
            vv[nx2]  = is64 ? (int)ei64[NEDGES + ee] : ei[NEDGES + ee];
            a0v[nx2] = ea[2 * ee]; a1v[nx2] = ea[2 * ee + 1];
        }
        // prefetch scales + gather for i+1
        su[nb] = sU[uu[nxt]]; sv[nb] = sV[vv[nxt]];
        gu[nb] = *(const u32x4*)(pre8 + (size_t)uu[nxt] * 256 + sub * 16);
        gv[nb] = *(const u32x4*)(pre8 + (size_t)vv[nxt] * 256 + 128 + sub * 16);

        // compute iteration i
        const float s_u = su[cb], s_v = sv[cb];
        const float K  = -128.f * (s_u + s_v);
        const float a0 = a0v[cur], a1 = a1v[cur];
        float s = 0.f;
        #pragma unroll
        for (int dw = 0; dw < 4; ++dw) {
            const unsigned pu = gu[cb][dw];
            const unsigned pv = gv[cb][dw];
            #pragma unroll
            for (int b = 0; b < 4; ++b) {
                const int j = dw * 4 + b;
                const float fu = (float)((pu >> (8 * b)) & 0xffu);  // v_cvt_f32_ubyteN
                const float fv = (float)((pv >> (8 * b)) & 0xffu);
                float bK  = fmaf(a0, r256v[j], fmaf(a1, r257v[j], K));
                float hid = fmaf(s_u, fu, fmaf(s_v, fv, bK));
                s = fmaf(fmaxf(hid, 0.f), w2v[j], s);
            }
        }

        s += __shfl_xor(s, 1, 64);
        s += __shfl_xor(s, 2, 64);
        s += __shfl_xor(s, 4, 64);
        if (sub == 0) out[e0 + i * ESTRIDE] = s + b2v;
    }
}

// =====================================================================
// Fallback (ws too small): monolithic f32-gather MFMA kernel
// =====================================================================
#define NWG 500
#define EPW 128

__global__ __launch_bounds__(256, 2)
void edgehead_mono(const float* __restrict__ h,
                   const int* __restrict__ ei,
                   const float* __restrict__ ea,
                   const float* __restrict__ W1,
                   const float* __restrict__ b1,
                   const float* __restrict__ W2,
                   const float* __restrict__ b2,
                   float* __restrict__ out)
{
    __shared__ short8 w1t8[128 * 32];
    __shared__ short8 w1e8[128 * 3];
    short* w1s  = (short*)w1t8;
    short* w1es = (short*)w1e8;
    const int tid = threadIdx.x;

    for (int idx = tid; idx < 256 * HID; idx += 256) {
        int k = idx >> 7, col = idx & 127;
        w1s[col * 256 + (k ^ ((col & 7) << 3))] = f2bf(W1[idx]);
    }
    if (tid < HID) {
        int col = tid, base = col * 24;
        w1es[base + 0] = f2bf(W1[256 * HID + col]);
        w1es[base + 1] = f2bf(W1[257 * HID + col]);
        w1es[base + 2] = f2bf(b1[col]);
        #pragma unroll
        for (int j = 3; j < 16; ++j) w1es[base + j] = 0;
    }
    __syncthreads();

    const int lane = tid & 63, wid = tid >> 6, l31 = lane & 31, grp = lane >> 5;
    const bool is64 = (ei[1] == 0) && (ei[3] == 0) && (ei[5] == 0) && (ei[7] == 0);
    const long long* ei64 = (const long long*)ei;

    float w2v[4];
    #pragma unroll
    for (int nt = 0; nt < 4; ++nt) w2v[nt] = W2[nt * 32 + l31];
    const float b2v = b2[0];

    for (int ebase = blockIdx.x * EPW + wid * 32; ebase < NEDGES; ebase += NWG * EPW) {
        const int e = ebase + l31;
        const int u = is64 ? (int)ei64[e] : ei[e];
        const int v = is64 ? (int)ei64[NEDGES + e] : ei[NEDGES + e];
        const float ea0 = ea[2 * e], ea1 = ea[2 * e + 1];
        const float* pu32 = h + (size_t)u * HID + grp * 8;
        const float* pv32 = h + (size_t)v * HID + grp * 8;

        f32x16 acc[4];
        #pragma unroll
        for (int nt = 0; nt < 4; ++nt)
            #pragma unroll
            for (int r = 0; r < 16; ++r) acc[nt][r] = 0.f;

        #pragma unroll
        for (int ks = 0; ks < 17; ++ks) {
            short8 af;
            if (ks < 16) {
                const float* p = (ks < 8) ? (pu32 + ks * 16) : (pv32 + (ks - 8) * 16);
                f32x4v a0 = *(const f32x4v*)(p);
                f32x4v a1 = *(const f32x4v*)(p + 4);
                af[0]=f2bf(a0.x); af[1]=f2bf(a0.y); af[2]=f2bf(a0.z); af[3]=f2bf(a0.w);
                af[4]=f2bf(a1.x); af[5]=f2bf(a1.y); af[6]=f2bf(a1.z); af[7]=f2bf(a1.w);
            } else {
                af[0] = grp ? (short)0 : f2bf(ea0);
                af[1] = grp ? (short)0 : f2bf(ea1);
                af[2] = grp ? (short)0 : (short)0x3F80;
                af[3]=0; af[4]=0; af[5]=0; af[6]=0; af[7]=0;
            }
            #pragma unroll
            for (int nt = 0; nt < 4; ++nt) {
                const int col = nt * 32 + l31;
                short8 bf = (ks < 16)
                    ? w1t8[col * 32 + ((ks * 2 + grp) ^ (l31 & 7))]
                    : w1e8[col * 3 + grp];
                acc[nt] = __builtin_amdgcn_mfma_f32_32x32x16_bf16(af, bf, acc[nt], 0, 0, 0);
            }
        }

        float pr[16];
        #pragma unroll
        for (int r = 0; r < 16; ++r) {
            float s = fmaxf(acc[0][r], 0.f) * w2v[0];
            s = fmaf(fmaxf(acc[1][r], 0.f), w2v[1], s);
            s = fmaf(fmaxf(acc[2][r], 0.f), w2v[2], s);
            s = fmaf(fmaxf(acc[3][r], 0.f), w2v[3], s);
            pr[r] = s;
        }
        #define FOLD(MASK, A, B) { \
            const bool hi = (lane & MASK) != 0; \
            float snd = hi ? pr[A] : pr[B]; \
            float kp  = hi ? pr[B] : pr[A]; \
            pr[A] = kp + __shfl_xor(snd, MASK, 64); }
        #pragma unroll
        for (int i = 0; i < 8; ++i) FOLD(1, i, i + 8)
        #pragma unroll
        for (int i = 0; i < 4; ++i) FOLD(2, i, i + 4)
        #pragma unroll
        for (int i = 0; i < 2; ++i) FOLD(4, i, i + 2)
        FOLD(8, 0, 1)
        #undef FOLD
        float val = pr[0] + __shfl_xor(pr[0], 16, 64);
        const int reff = ((lane & 1) << 3) | ((lane & 2) << 1) | ((lane & 4) >> 1) | ((lane & 8) >> 3);
        const int row  = (reff & 3) + ((reff >> 2) << 3) + grp * 4;
        if ((lane & 16) == 0) out[ebase + row] = val + b2v;
    }
}

extern "C" void kernel_launch(void* const* d_in, const int* in_sizes, int n_in,
                              void* d_out, int out_size, void* d_ws, size_t ws_size,
                              hipStream_t stream) {
    const float* h  = (const float*)d_in[0];
    const int*   ei = (const int*)d_in[1];
    const float* ea = (const float*)d_in[2];
    const float* W1 = (const float*)d_in[3];
    const float* b1 = (const float*)d_in[4];
    const float* W2 = (const float*)d_in[5];
    const float* b2 = (const float*)d_in[6];
    float* out = (float*)d_out;

    const size_t pre_bytes = (size_t)NNODES * 256;            // 12.8 MB
    const size_t s_bytes   = (size_t)NNODES * sizeof(float);  // 200 KB each
    const size_t need = pre_bytes + 2 * s_bytes;
    if (ws_size >= need) {
        unsigned char* pre8 = (unsigned char*)d_ws;
        float* sUp = (float*)((char*)d_ws + pre_bytes);
        float* sVp = (float*)((char*)d_ws + pre_bytes + s_bytes);
        const int mblocks = ((NNODES + 127) / 128) * 2;   // 782
        hipLaunchKernelGGL(gemm_pre, dim3(mblocks), dim3(256), 0, stream,
                           h, W1, b1, pre8, sUp, sVp);
        hipLaunchKernelGGL(edge_apply, dim3(NBLK), dim3(256), 0, stream,
                           pre8, sUp, sVp, ei, ea, W1, W2, b2, out);
    } else {
        hipLaunchKernelGGL(edgehead_mono, dim3(NWG), dim3(256), 0, stream,
                           h, ei, ea, W1, b1, W2, b2, out);
    }
}

// Round 11
// 51.254 us; speedup vs baseline: 2.7703x; 2.7703x over previous
//
#include <hip/hip_runtime.h>
#include <hip/hip_bf16.h>

#define NNODES 50000
#define NEDGES 640000
#define HID 128

typedef __attribute__((ext_vector_type(8)))  short  short8;
typedef __attribute__((ext_vector_type(16))) float  f32x16;
typedef __attribute__((ext_vector_type(4)))  float  f32x4v;
typedef __attribute__((ext_vector_type(4)))  unsigned int u32x4;

static __device__ __forceinline__ short f2bf(float x) {
    return __builtin_bit_cast(short, __float2bfloat16(x));
}

// =====================================================================
// Kernel 1: pre = [h*W1u + b1 | h*W1v], quantized to uint8 (bias 128)
// with per-(node,half) scale = rowmax/127. Unchanged from R8/R9 (~9us).
// =====================================================================
__global__ __launch_bounds__(256, 3)
void gemm_pre(const float* __restrict__ h,
              const float* __restrict__ W1,
              const float* __restrict__ b1,
              unsigned char* __restrict__ pre8,
              float* __restrict__ sU,
              float* __restrict__ sV)
{
    __shared__ short8 w1s8[128 * 16];   // 32 KB swizzled
    short* w1s = (short*)w1s8;
    const int tid  = threadIdx.x;
    const int mblk = blockIdx.x >> 1;
    const int ch   = blockIdx.x & 1;    // 0: u-half (+b1), 1: v-half

    for (int idx = tid; idx < 128 * 128; idx += 256) {
        int k = idx >> 7, col = idx & 127;
        float val = W1[(ch * 128 + k) * HID + col];
        int c = (k >> 3) ^ (col & 7);
        w1s[col * 128 + c * 8 + (k & 7)] = f2bf(val);
    }
    __syncthreads();

    const int lane = tid & 63;
    const int wid  = tid >> 6;
    const int l31  = lane & 31;
    const int grp  = lane >> 5;

    const int mb = mblk * 128 + wid * 32;
    int arow = mb + l31;
    if (arow > NNODES - 1) arow = NNODES - 1;
    const float* ap = h + (size_t)arow * HID + grp * 8;

    f32x16 acc[4];
    #pragma unroll
    for (int nt = 0; nt < 4; ++nt)
        #pragma unroll
        for (int r = 0; r < 16; ++r) acc[nt][r] = 0.f;

    #pragma unroll
    for (int ks = 0; ks < 8; ++ks) {
        f32x4v a0 = *(const f32x4v*)(ap + ks * 16);
        f32x4v a1 = *(const f32x4v*)(ap + ks * 16 + 4);
        short8 af;
        af[0] = f2bf(a0.x); af[1] = f2bf(a0.y); af[2] = f2bf(a0.z); af[3] = f2bf(a0.w);
        af[4] = f2bf(a1.x); af[5] = f2bf(a1.y); af[6] = f2bf(a1.z); af[7] = f2bf(a1.w);
        #pragma unroll
        for (int nt = 0; nt < 4; ++nt) {
            const int col = nt * 32 + l31;
            short8 bf = w1s8[col * 16 + ((ks * 2 + grp) ^ (col & 7))];
            acc[nt] = __builtin_amdgcn_mfma_f32_32x32x16_bf16(af, bf, acc[nt], 0, 0, 0);
        }
    }

    float b1v[4];
    #pragma unroll
    for (int nt = 0; nt < 4; ++nt)
        b1v[nt] = ch ? 0.f : b1[nt * 32 + l31];

    #pragma unroll
    for (int r = 0; r < 16; ++r) {
        float m = 0.f;
        #pragma unroll
        for (int nt = 0; nt < 4; ++nt) {
            float val = acc[nt][r] + b1v[nt];
            acc[nt][r] = val;
            m = fmaxf(m, fabsf(val));
        }
        m = fmaxf(m, __shfl_xor(m, 1, 64));
        m = fmaxf(m, __shfl_xor(m, 2, 64));
        m = fmaxf(m, __shfl_xor(m, 4, 64));
        m = fmaxf(m, __shfl_xor(m, 8, 64));
        m = fmaxf(m, __shfl_xor(m, 16, 64));

        const int row = mb + ((r & 3) + 8 * (r >> 2) + 4 * grp);
        if (row < NNODES) {
            const float inv = (m > 0.f) ? (127.f / m) : 0.f;
            if (l31 == 0) (ch ? sV : sU)[row] = m * (1.f / 127.f);
            #pragma unroll
            for (int nt = 0; nt < 4; ++nt) {
                int q = (int)rintf(acc[nt][r] * inv) + 128;
                pre8[(size_t)row * 256 + ch * 128 + nt * 32 + l31] = (unsigned char)q;
            }
        }
    }
}

// =====================================================================
// Kernel 2: per-edge apply on int8 pre. 8 lanes/edge, 16 cols each.
// __launch_bounds__(256,4): PROVEN no-spill (VGPR cap 128). Do NOT raise
// min-waves: (256,6) and (256,8) both spilled (R6, R9) — the 48-reg
// constant bank + pipeline state needs > the squeezed budget.
// Single-round balanced grid: 1000 blocks x 32 edges x 20 iters = 640000,
// 1000 <= 1024 resident at 4 blk/CU -> no tail round.
// 2-deep gather pipeline: idx[i+3] (linear) / gather+ea[i+2] / compute[i].
// =====================================================================
#define NBLK 1000
#define EPI  32
#define ESTRIDE (NBLK * EPI)
#define NITER 20

__global__ __launch_bounds__(256, 4)
void edge_apply(const unsigned char* __restrict__ pre8,
                const float* __restrict__ sU,
                const float* __restrict__ sV,
                const int* __restrict__ ei,
                const float* __restrict__ ea,
                const float* __restrict__ W1,
                const float* __restrict__ W2,
                const float* __restrict__ b2,
                float* __restrict__ out)
{
    const int tid = threadIdx.x;
    const int sub = tid & 7;
    const int e0  = blockIdx.x * EPI + (tid >> 3);

    float r256v[16], r257v[16], w2v[16];
    #pragma unroll
    for (int q = 0; q < 4; ++q) {
        f32x4v a = *(const f32x4v*)(W1 + 256 * HID + sub * 16 + q * 4);
        f32x4v b = *(const f32x4v*)(W1 + 257 * HID + sub * 16 + q * 4);
        f32x4v c = *(const f32x4v*)(W2 + sub * 16 + q * 4);
        r256v[q*4+0]=a.x; r256v[q*4+1]=a.y; r256v[q*4+2]=a.z; r256v[q*4+3]=a.w;
        r257v[q*4+0]=b.x; r257v[q*4+1]=b.y; r257v[q*4+2]=b.z; r257v[q*4+3]=b.w;
        w2v [q*4+0]=c.x; w2v [q*4+1]=c.y; w2v [q*4+2]=c.z; w2v [q*4+3]=c.w;
    }
    const float b2v = b2[0];

    const bool is64 = (ei[1] == 0) && (ei[3] == 0) && (ei[5] == 0) && (ei[7] == 0);
    const long long* ei64 = (const long long*)ei;

    // pipeline state: idx 4-slot (loaded 3 ahead), gather/ea/scales 3-slot
    // (issued 2 ahead). All rotation indices compile-time via full unroll.
    int   uu[4], vv[4];
    float a0v[3], a1v[3];
    float su[3], sv[3];
    u32x4 gu[3], gv[3];

    #pragma unroll
    for (int p = 0; p < 3; ++p) {
        const int ee = e0 + p * ESTRIDE;
        uu[p] = is64 ? (int)ei64[ee] : ei[ee];
        vv[p] = is64 ? (int)ei64[NEDGES + ee] : ei[NEDGES + ee];
    }
    #pragma unroll
    for (int p = 0; p < 2; ++p) {
        const int ee = e0 + p * ESTRIDE;
        su[p] = sU[uu[p]]; sv[p] = sV[vv[p]];
        gu[p] = *(const u32x4*)(pre8 + (size_t)uu[p] * 256 + sub * 16);
        gv[p] = *(const u32x4*)(pre8 + (size_t)vv[p] * 256 + 128 + sub * 16);
        a0v[p] = ea[2 * ee]; a1v[p] = ea[2 * ee + 1];
    }

    #pragma unroll
    for (int i = 0; i < NITER; ++i) {
        // stage A: idx bundle i+3 (linear stream, clamped at tail)
        {
            const int s4 = (i + 3) & 3;
            const int ee = (i + 3 < NITER) ? (e0 + (i + 3) * ESTRIDE) : e0;
            uu[s4] = is64 ? (int)ei64[ee] : ei[ee];
            vv[s4] = is64 ? (int)ei64[NEDGES + ee] : ei[NEDGES + ee];
        }
        // stage B: gather + scales + ea for i+2 (idx loaded 2 iters ago)
        {
            const int g3 = (i + 2) % 3;
            const int s4 = (i + 2) & 3;
            const int ee = (i + 2 < NITER) ? (e0 + (i + 2) * ESTRIDE) : e0;
            su[g3] = sU[uu[s4]]; sv[g3] = sV[vv[s4]];
            gu[g3] = *(const u32x4*)(pre8 + (size_t)uu[s4] * 256 + sub * 16);
            gv[g3] = *(const u32x4*)(pre8 + (size_t)vv[s4] * 256 + 128 + sub * 16);
            a0v[g3] = ea[2 * ee]; a1v[g3] = ea[2 * ee + 1];
        }
        // stage C: compute iteration i
        {
            const int c3 = i % 3;
            const float s_u = su[c3], s_v = sv[c3];
            const float K  = -128.f * (s_u + s_v);
            const float a0 = a0v[c3], a1 = a1v[c3];
            float s = 0.f;
            #pragma unroll
            for (int dw = 0; dw < 4; ++dw) {
                const unsigned pu = gu[c3][dw];
                const unsigned pv = gv[c3][dw];
                #pragma unroll
                for (int b = 0; b < 4; ++b) {
                    const int j = dw * 4 + b;
                    const float fu = (float)((pu >> (8 * b)) & 0xffu);  // v_cvt_f32_ubyteN
                    const float fv = (float)((pv >> (8 * b)) & 0xffu);
                    float bK  = fmaf(a0, r256v[j], fmaf(a1, r257v[j], K));
                    float hid = fmaf(s_u, fu, fmaf(s_v, fv, bK));
                    s = fmaf(fmaxf(hid, 0.f), w2v[j], s);
                }
            }
            s += __shfl_xor(s, 1, 64);
            s += __shfl_xor(s, 2, 64);
            s += __shfl_xor(s, 4, 64);
            if (sub == 0) out[e0 + i * ESTRIDE] = s + b2v;
        }
    }
}

// =====================================================================
// Fallback (ws too small): monolithic f32-gather MFMA kernel
// =====================================================================
#define NWG 500
#define EPW 128

__global__ __launch_bounds__(256, 2)
void edgehead_mono(const float* __restrict__ h,
                   const int* __restrict__ ei,
                   const float* __restrict__ ea,
                   const float* __restrict__ W1,
                   const float* __restrict__ b1,
                   const float* __restrict__ W2,
                   const float* __restrict__ b2,
                   float* __restrict__ out)
{
    __shared__ short8 w1t8[128 * 32];
    __shared__ short8 w1e8[128 * 3];
    short* w1s  = (short*)w1t8;
    short* w1es = (short*)w1e8;
    const int tid = threadIdx.x;

    for (int idx = tid; idx < 256 * HID; idx += 256) {
        int k = idx >> 7, col = idx & 127;
        w1s[col * 256 + (k ^ ((col & 7) << 3))] = f2bf(W1[idx]);
    }
    if (tid < HID) {
        int col = tid, base = col * 24;
        w1es[base + 0] = f2bf(W1[256 * HID + col]);
        w1es[base + 1] = f2bf(W1[257 * HID + col]);
        w1es[base + 2] = f2bf(b1[col]);
        #pragma unroll
        for (int j = 3; j < 16; ++j) w1es[base + j] = 0;
    }
    __syncthreads();

    const int lane = tid & 63, wid = tid >> 6, l31 = lane & 31, grp = lane >> 5;
    const bool is64 = (ei[1] == 0) && (ei[3] == 0) && (ei[5] == 0) && (ei[7] == 0);
    const long long* ei64 = (const long long*)ei;

    float w2v[4];
    #pragma unroll
    for (int nt = 0; nt < 4; ++nt) w2v[nt] = W2[nt * 32 + l31];
    const float b2v = b2[0];

    for (int ebase = blockIdx.x * EPW + wid * 32; ebase < NEDGES; ebase += NWG * EPW) {
        const int e = ebase + l31;
        const int u = is64 ? (int)ei64[e] : ei[e];
        const int v = is64 ? (int)ei64[NEDGES + e] : ei[NEDGES + e];
        const float ea0 = ea[2 * e], ea1 = ea[2 * e + 1];
        const float* pu32 = h + (size_t)u * HID + grp * 8;
        const float* pv32 = h + (size_t)v * HID + grp * 8;

        f32x16 acc[4];
        #pragma unroll
        for (int nt = 0; nt < 4; ++nt)
            #pragma unroll
            for (int r = 0; r < 16; ++r) acc[nt][r] = 0.f;

        #pragma unroll
        for (int ks = 0; ks < 17; ++ks) {
            short8 af;
            if (ks < 16) {
                const float* p = (ks < 8) ? (pu32 + ks * 16) : (pv32 + (ks - 8) * 16);
                f32x4v a0 = *(const f32x4v*)(p);
                f32x4v a1 = *(const f32x4v*)(p + 4);
                af[0]=f2bf(a0.x); af[1]=f2bf(a0.y); af[2]=f2bf(a0.z); af[3]=f2bf(a0.w);
                af[4]=f2bf(a1.x); af[5]=f2bf(a1.y); af[6]=f2bf(a1.z); af[7]=f2bf(a1.w);
            } else {
                af[0] = grp ? (short)0 : f2bf(ea0);
                af[1] = grp ? (short)0 : f2bf(ea1);
                af[2] = grp ? (short)0 : (short)0x3F80;
                af[3]=0; af[4]=0; af[5]=0; af[6]=0; af[7]=0;
            }
            #pragma unroll
            for (int nt = 0; nt < 4; ++nt) {
                const int col = nt * 32 + l31;
                short8 bf = (ks < 16)
                    ? w1t8[col * 32 + ((ks * 2 + grp) ^ (l31 & 7))]
                    : w1e8[col * 3 + grp];
                acc[nt] = __builtin_amdgcn_mfma_f32_32x32x16_bf16(af, bf, acc[nt], 0, 0, 0);
            }
        }

        float pr[16];
        #pragma unroll
        for (int r = 0; r < 16; ++r) {
            float s = fmaxf(acc[0][r], 0.f) * w2v[0];
            s = fmaf(fmaxf(acc[1][r], 0.f), w2v[1], s);
            s = fmaf(fmaxf(acc[2][r], 0.f), w2v[2], s);
            s = fmaf(fmaxf(acc[3][r], 0.f), w2v[3], s);
            pr[r] = s;
        }
        #define FOLD(MASK, A, B) { \
            const bool hi = (lane & MASK) != 0; \
            float snd = hi ? pr[A] : pr[B]; \
            float kp  = hi ? pr[B] : pr[A]; \
            pr[A] = kp + __shfl_xor(snd, MASK, 64); }
        #pragma unroll
        for (int i = 0; i < 8; ++i) FOLD(1, i, i + 8)
        #pragma unroll
        for (int i = 0; i < 4; ++i) FOLD(2, i, i + 4)
        #pragma unroll
        for (int i = 0; i < 2; ++i) FOLD(4, i, i + 2)
        FOLD(8, 0, 1)
        #undef FOLD
        float val = pr[0] + __shfl_xor(pr[0], 16, 64);
        const int reff = ((lane & 1) << 3) | ((lane & 2) << 1) | ((lane & 4) >> 1) | ((lane & 8) >> 3);
        const int row  = (reff & 3) + ((reff >> 2) << 3) + grp * 4;
        if ((lane & 16) == 0) out[ebase + row] = val + b2v;
    }
}

extern "C" void kernel_launch(void* const* d_in, const int* in_sizes, int n_in,
                              void* d_out, int out_size, void* d_ws, size_t ws_size,
                              hipStream_t stream) {
    const float* h  = (const float*)d_in[0];
    const int*   ei = (const int*)d_in[1];
    const float* ea = (const float*)d_in[2];
    const float* W1 = (const float*)d_in[3];
    const float* b1 = (const float*)d_in[4];
    const float* W2 = (const float*)d_in[5];
    const float* b2 = (const float*)d_in[6];
    float* out = (float*)d_out;

    const size_t pre_bytes = (size_t)NNODES * 256;            // 12.8 MB
    const size_t s_bytes   = (size_t)NNODES * sizeof(float);  // 200 KB each
    const size_t need = pre_bytes + 2 * s_bytes;
    if (ws_size >= need) {
        unsigned char* pre8 = (unsigned char*)d_ws;
        float* sUp = (float*)((char*)d_ws + pre_bytes);
        float* sVp = (float*)((char*)d_ws + pre_bytes + s_bytes);
        const int mblocks = ((NNODES + 127) / 128) * 2;   // 782
        hipLaunchKernelGGL(gemm_pre, dim3(mblocks), dim3(256), 0, stream,
                           h, W1, b1, pre8, sUp, sVp);
        hipLaunchKernelGGL(edge_apply, dim3(NBLK), dim3(256), 0, stream,
                           pre8, sUp, sVp, ei, ea, W1, W2, b2, out);
    } else {
        hipLaunchKernelGGL(edgehead_mono, dim3(NWG), dim3(256), 0, stream,
                           h, ei, ea, W1, b1, W2, b2, out);
    }
}